// Round 5
// baseline (3856.257 us; speedup 1.0000x reference)
//
#include <hip/hip_runtime.h>

typedef unsigned short u16;
typedef unsigned int   u32;
typedef unsigned long long u64;
typedef __attribute__((ext_vector_type(8))) short s8v;   // 8 x bf16 (4 VGPRs)
typedef __attribute__((ext_vector_type(4))) float f4v;   // MFMA accumulator

#define DEVI __device__ __forceinline__

// ---- problem constants ----
#define B_  16
#define N_  5
#define T_  10
#define H_  512
#define E_  250
#define V_  30000
#define F_  2048
#define FH  2048   // 4H
#define H2  1024   // 2H
#define NCOMP 128  // compute blocks: dir(2) x 64 col-groups, 2 waves each

// ---- static device scratch (no d_ws dependence) ----
__device__ u32   g_flag;                  // 1 = inputs are float32, 0 = bf16
__device__ u32   g_slot0[NCOMP];          // wave0 (layer-0) epoch per block
__device__ u32   g_slot1[NCOMP];          // wave1 (layer-1) epoch per block
__device__ __attribute__((aligned(64))) u16   g_H0[4*2*16*512];   // [(dir*2+par)][plane][16][512]
__device__ __attribute__((aligned(64))) u16   g_H1[4*2*16*512];
__device__ __attribute__((aligned(64))) float g_cinit[16*512];
__device__ __attribute__((aligned(64))) u16   g_A1[2*2*16*1024];  // [which][plane][16][1024]
__device__ __attribute__((aligned(64))) u16   g_X1[4*2*10*16*1024]; // [callmod4][plane][row*16+b][1024]
__device__ __attribute__((aligned(64))) u16   g_OUT1[2*800*1024]; // [plane][orow][1024]
__device__ __attribute__((aligned(64))) u16   g_TOK[800*256];     // [(b*5+n)*10+r][256] bf16

DEVI f4v MFMA(s8v a, s8v b, f4v c){ return __builtin_amdgcn_mfma_f32_16x16x32_bf16(a,b,c,0,0,0); }
DEVI float bf2f(u16 u){ union{u32 i; float f;} v; v.i = ((u32)u)<<16; return v.f; }
DEVI u16 f2bf(float f){ union{float f; u32 i;} v; v.f = f; u32 i = v.i + 0x7fffu + ((v.i>>16)&1u); return (u16)(i>>16); }
DEVI float sigm(float x){ return 1.0f/(1.0f+__expf(-x)); }
DEVI float tanhfast(float x){ float e = __expf(2.0f*x); return 1.0f - 2.0f/(e+1.0f); }

DEVI s8v ld16(const u16* p){ return *(const s8v*)p; }                 // 16B-aligned, cached
DEVI s8v ld16u(const u16* p){ s8v a; __builtin_memcpy(&a, p, 16); return a; }

// bypassing 16B load issue (sc0 sc1 -> served at mall, no stale L1/L2). Completion is
// tracked manually via counted vmcnt waits tied to the dest regs ("+v") so consuming
// MFMAs cannot be scheduled above the wait. Extra OLDER outstanding ops (e.g. slot/OUT
// stores) only make counted waits more conservative -- never unsafe.
DEVI void ldc(s8v& d, const u16* p){
  asm volatile("global_load_dwordx4 %0, %1, off sc0 sc1" : "=v"(d) : "v"(p));
}
template<int N> DEVI void waitv(s8v& a){
  asm volatile("s_waitcnt vmcnt(%1)" : "+v"(a) : "n"(N));
}
template<int N> DEVI void waitv2(s8v& a, s8v& b){
  asm volatile("s_waitcnt vmcnt(%2)" : "+v"(a), "+v"(b) : "n"(N));
}

// coherent write-through 2B store (sc0 sc1): visible at mall, never dirty in L2
DEVI void st2c(u16* p, u16 v){
  asm volatile("global_store_short %0, %1, off sc0 sc1" :: "v"(p), "v"((u32)v) : "memory");
}

// dtype-flexible element accessors (flag is wave-uniform)
DEVI u16 ldw(const void* W, size_t idx, int f32){
  return f32 ? f2bf(((const float*)W)[idx]) : ((const u16*)W)[idx];
}
DEVI float ldwf(const void* W, size_t idx, int f32){
  return f32 ? ((const float*)W)[idx] : bf2f(((const u16*)W)[idx]);
}
DEVI s8v ldA8(const void* A, size_t idx, int f32){
  if(f32){
    const float* p = (const float*)A + idx;
    s8v a;
    #pragma unroll
    for(int j=0;j<8;++j) a[j] = (short)f2bf(p[j]);
    return a;
  }
  return ld16u((const u16*)A + idx);
}
DEVI s8v gatherBf(const void* W, int ld, int row0, int col, int f32){
  s8v r;
  #pragma unroll
  for(int j=0;j<8;++j) r[j] = (short)ldw(W, (size_t)(row0+j)*ld + col, f32);
  return r;
}

// repeat macros (manual unroll keeps every index/template-arg a literal constant)
#define RPT4(M,b)  M(b) M((b)+1) M((b)+2) M((b)+3)
#define RPT8(M,b)  RPT4(M,b) RPT4(M,(b)+4)
#define RPT16(M,b) RPT8(M,b) RPT8(M,(b)+8)

// ---- decoupled dataflow flags ----
DEVI void publish_slot(u32* slot, u32 val){
  asm volatile("s_waitcnt vmcnt(0)" ::: "memory");   // drain stores issued so far
  if((threadIdx.x & 63)==0)
    __hip_atomic_store(slot, val, __ATOMIC_RELAXED, __HIP_MEMORY_SCOPE_SYSTEM);
}
// poll 64 slots (one per lane) until all >= tgt; end with clean vmcnt for counted phases
DEVI void poll_n64(u32* base, u32 tgt){
  int l = threadIdx.x & 63;
  for(;;){
    u32 a = __hip_atomic_load(&base[l], __ATOMIC_RELAXED, __HIP_MEMORY_SCOPE_SYSTEM);
    if(__all((int)(a>=tgt))) break;
    __builtin_amdgcn_s_sleep(1);
  }
  asm volatile("s_waitcnt vmcnt(0)" ::: "memory");
}
// poll all 128 slots (two per lane)
DEVI void poll_n128(u32* base, u32 tgt){
  int l = threadIdx.x & 63;
  for(;;){
    u32 a = __hip_atomic_load(&base[l],    __ATOMIC_RELAXED, __HIP_MEMORY_SCOPE_SYSTEM);
    u32 b = __hip_atomic_load(&base[l+64], __ATOMIC_RELAXED, __HIP_MEMORY_SCOPE_SYSTEM);
    if(__all((int)(a>=tgt && b>=tgt))) break;
    __builtin_amdgcn_s_sleep(1);
  }
  asm volatile("s_waitcnt vmcnt(0)" ::: "memory");
}

// =====================  K0: dtype sniff + flag state reset  =====================
__global__ __launch_bounds__(64) void k0(const void* img){
  int l = threadIdx.x;
  const u16* p = (const u16*)img;
  int bad = 0;
  #pragma unroll
  for(int i=0;i<4;++i){
    float v = bf2f(p[l + 64*i]);      // f32 data => half these are mantissa garbage
    if(!(fabsf(v) <= 1e4f)) bad = 1;  // catches huge exponents AND NaN
  }
  unsigned long long mb = __ballot(bad);
  g_slot0[l] = 0u; g_slot0[l+64] = 0u;
  g_slot1[l] = 0u; g_slot1[l+64] = 0u;
  if(l==0){ g_flag = (mb != 0ull) ? 1u : 0u; }
}

// =====================  K_tok: compact bf16 token-embedding table  =====================
__global__ __launch_bounds__(256) void k_tok(const int* caps, const void* emb){
  int f32 = (int)g_flag;
  int idx = blockIdx.x*256 + threadIdx.x;     // 0 .. 800*256-1
  int bnr = idx>>8, e = idx&255;
  int tok = caps[bnr];
  u16 v = (e < E_) ? ldw(emb, (size_t)tok*E_ + e, f32) : (u16)0;
  g_TOK[idx] = v;
}

// =====================  K1a: A1 = relu(img@Wh1+bh1), C1 = relu(img@Wc1+bc1) =====================
__global__ __launch_bounds__(256) void k1a(const void* img, const void* Wh1, const void* bh1,
                                           const void* Wc1, const void* bc1){
  int f32 = (int)g_flag;
  int w = threadIdx.x>>6, l = threadIdx.x&63, q = l>>4, c = l&15, m = l&15;
  int widx = blockIdx.x*4 + w;         // 0..127
  int which = widx>>6;                 // 0=h path, 1=c path
  int ct    = widx&63;                 // 64 col tiles
  const void* W    = which? Wc1 : Wh1;
  const void* bias = which? bc1 : bh1;
  int col = ct*16 + c;
  f4v acc = {0.f,0.f,0.f,0.f};
  #pragma unroll 4
  for(int kc=0; kc<64; ++kc){
    s8v a = ldA8(img, (size_t)m*F_ + kc*32 + q*8, f32);
    s8v b = gatherBf(W, H2, kc*32+q*8, col, f32);
    acc = MFMA(a,b,acc);
  }
  float bi = ldwf(bias, col, f32);
  #pragma unroll
  for(int r=0;r<4;++r){
    float v = fmaxf(acc[r]+bi, 0.f);
    u16 hi = f2bf(v); u16 lo = f2bf(v - bf2f(hi));
    int rowb = q*4+r;
    g_A1[(size_t)(which*2+0)*B_*H2 + (size_t)rowb*H2 + col] = hi;
    g_A1[(size_t)(which*2+1)*B_*H2 + (size_t)rowb*H2 + col] = lo;
  }
}

// =====================  K1b: h,c = relu(A1@Wh2+bh2) etc; init H bufs (parity 0), cinit =====================
__global__ __launch_bounds__(256) void k1b(const void* Wh2, const void* bh2,
                                           const void* Wc2, const void* bc2){
  int f32 = (int)g_flag;
  int w = threadIdx.x>>6, l = threadIdx.x&63, q = l>>4, c = l&15, m = l&15;
  int widx = blockIdx.x*4 + w;         // 0..63
  int which = widx>>5;                 // 0=h, 1=c
  int ct    = widx&31;                 // 32 col tiles (H=512)
  const void* W    = which? Wc2 : Wh2;
  const void* bias = which? bc2 : bh2;
  const u16* Ab    = g_A1 + (size_t)which*2*B_*H2;
  int col = ct*16 + c;
  f4v acc = {0.f,0.f,0.f,0.f};
  #pragma unroll 4
  for(int kc=0; kc<32; ++kc){
    s8v ah = ld16(Ab + (size_t)m*H2 + kc*32 + q*8);
    s8v al = ld16(Ab + (size_t)B_*H2 + (size_t)m*H2 + kc*32 + q*8);
    s8v b  = gatherBf(W, H_, kc*32+q*8, col, f32);
    acc = MFMA(ah,b,acc);
    acc = MFMA(al,b,acc);
  }
  float bi = ldwf(bias, col, f32);
  #pragma unroll
  for(int r=0;r<4;++r){
    float v = fmaxf(acc[r]+bi, 0.f);
    int rowb = q*4+r;
    if(which==0){
      u16 hi = f2bf(v); u16 lo = f2bf(v - bf2f(hi));
      #pragma unroll
      for(int dir=0; dir<2; ++dir){
        size_t base = (size_t)(dir*2+0)*16384;      // parity 0
        g_H0[base + 0*8192 + rowb*512 + col] = hi;  g_H0[base + 1*8192 + rowb*512 + col] = lo;
        g_H1[base + 0*8192 + rowb*512 + col] = hi;  g_H1[base + 1*8192 + rowb*512 + col] = lo;
      }
    } else {
      g_cinit[(size_t)rowb*H_ + col] = v;
    }
  }
}

// gate combine: acc holds G[batch=4q+r][col c], cols = gate(c>>2) x hcol(c&3).
DEVI float gate_combine(f4v acc, float& cs, int l){
  int base = (l & 48) | (l & 3);
  int sel  = (l >> 2) & 3;
  float G[4];
  #pragma unroll
  for(int gg=0; gg<4; ++gg){
    int src = base | (gg<<2);
    float a0 = __shfl(acc[0], src, 64);
    float a1 = __shfl(acc[1], src, 64);
    float a2 = __shfl(acc[2], src, 64);
    float a3 = __shfl(acc[3], src, 64);
    float x = (sel&1)? a1 : a0;
    float y = (sel&1)? a3 : a2;
    G[gg] = (sel&2)? y : x;
  }
  float iG = sigm(G[0]);
  float fG = sigm(G[1]);
  float gG = tanhfast(G[2]);
  float oG = sigm(G[3]);
  cs = fG*cs + iG*gG;
  return oG * tanhfast(cs);
}

// =====================  K2: DECOUPLED + BUBBLE-FILLED persistent bilstm2 x 50  =====================
// 128 blocks x 128 threads. wave0 = layer-0 engine (per-step dep: same-dir wave0 peers).
// wave1 = layer-1 engine (per-step dep: same-dir wave1 peers; X1 dep is call-granular).
// Pipeline rotation: wave1 computes the X-phase of step s+1 AFTER publish(s) -- it fills
// the publish->peer-detect bubble and leaves only {detect, H1-stream, MFMA, gates, 4-store
// drain} on the recurrence chain. Store-split: publish drains only the recurrence-critical
// H stores; X1/OUT1 stores issue post-publish (except the last step of a call, where X1
// drains pre-publish so the call-granular freeze flag remains correct).
// LDS sw is lane-major ([kc][lane][8]) -> conflict-free ds_read_b128.
__global__ __launch_bounds__(128) void k2(const void* Wih0f, const void* Whh0f, const void* b0f,
                                          const void* Wih0b, const void* Whh0b, const void* b0b,
                                          const void* Wih1f, const void* Whh1f, const void* b1f,
                                          const void* Wih1b, const void* Whh1b, const void* b1b){
  __shared__ u16 sw[2*24576];                  // 96 KB: [tile][kc48][lane64][j8]
  int tid = threadIdx.x;
  int blk = blockIdx.x;
  int f32 = (int)g_flag;
  int wv  = tid>>6;                            // 0 = layer-0 wave, 1 = layer-1 wave
  int l   = tid&63;
  int q = l>>4, c = l&15, m = l&15;
  int l8 = l*8;                                // lane-major LDS read offset (u16 units)
  int dir = blk>>6; int blkd = blk&63;
  int hb  = blkd*8;                            // 8 owned h-cols
  int gc0 = (c>>2)*512 + hb + (c&3);           // lane's G-column, tile 0
  int gc1 = gc0 + 4;                           // tile 1
  int bo  = q*4 + (c>>2);                      // owned batch row
  int hc0 = hb + (c&3), hc1 = hc0 + 4;         // owned h-cols

  const void* Wih0 = dir? Wih0b : Wih0f;
  const void* Whh0 = dir? Whh0b : Whh0f;
  const void* b0   = dir? b0b   : b0f;
  const void* Wih1 = dir? Wih1b : Wih1f;
  const void* Whh1 = dir? Whh1b : Whh1f;
  const void* b1   = dir? b1b   : b1f;

  // ---- layer-1 B-fragments for both tiles in LDS (lane-major layout) ----
  for(int tt=0; tt<2; ++tt){
    int gb = hb + tt*4;
    for(int ii=tid; ii<24576; ii+=128){
      int kc = ii>>9;
      int lane = (ii>>3)&63;
      int j  = ii&7;
      int cc = lane&15, qq = lane>>4;
      int gc = (cc>>2)*512 + gb + (cc&3);
      int rowk = kc*32+qq*8+j;
      sw[tt*24576+ii] = (rowk < H2) ? ldw(Wih1, (size_t)rowk*FH + gc, f32)
                                    : ldw(Whh1, (size_t)(rowk-H2)*FH + gc, f32);
    }
  }

  // ---- per-wave persistent state ----
  s8v w0a[16], w0b[16], wxa[8], wxb[8];        // wave0 only: layer-0 B-frags in regs
  float cA0=0.f, cA1=0.f, biasA0=0.f, biasA1=0.f;   // wave0 (layer-0 cell state)
  float cB0=0.f, cB1=0.f, biasB0=0.f, biasB1=0.f;   // wave1 (layer-1 cell state)
  if(wv==0){
    #pragma unroll
    for(int kc=0;kc<16;++kc){
      #pragma unroll
      for(int j=0;j<8;++j){
        int rowk = kc*32+q*8+j;
        w0a[kc][j] = (short)ldw(Whh0, (size_t)rowk*FH + gc0, f32);
        w0b[kc][j] = (short)ldw(Whh0, (size_t)rowk*FH + gc1, f32);
      }
    }
    #pragma unroll
    for(int kc=0;kc<8;++kc){
      #pragma unroll
      for(int j=0;j<8;++j){
        int rowk = kc*32+q*8+j;
        wxa[kc][j] = (rowk<E_)? (short)ldw(Wih0, (size_t)rowk*FH + gc0, f32) : (short)0;
        wxb[kc][j] = (rowk<E_)? (short)ldw(Wih0, (size_t)rowk*FH + gc1, f32) : (short)0;
      }
    }
    biasA0 = ldwf(b0, gc0, f32); biasA1 = ldwf(b0, gc1, f32);
    cA0 = g_cinit[(size_t)bo*H_ + hc0]; cA1 = g_cinit[(size_t)bo*H_ + hc1];
  } else {
    biasB0 = ldwf(b1, gc0, f32); biasB1 = ldwf(b1, gc1, f32);
    cB0 = g_cinit[(size_t)bo*H_ + hc0]; cB1 = g_cinit[(size_t)bo*H_ + hc1];
  }
  __syncthreads();                             // LDS ready; waves decouple from here on

  if(wv==0){
    // =================== layer-0 engine: 275 free-running steps ===================
    u32 i0 = 0; int p0 = 0;
    for(int k=0; k<50; ++k){
      int Lk = k/5 + 1; int n0 = k - (k/5)*5;
      if(k>=4){
        // X1 buffer recycle guard: wave1 (both dirs) must have finished call k-4
        u32 need = 0;
        for(int j=0;j<k-3;++j) need += (u32)(j/5+1);   // S(k-3)
        poll_n128(g_slot1, need);
      }
      for(int s=0; s<Lk; ++s){
        int row = dir ? (Lk-1-s) : s;
        const u16* er = g_TOK + ((size_t)(m*N_ + n0)*T_ + row)*256;
        const u16* Hr = g_H0 + (size_t)(dir*2 + p0)*16384;
        f4v A0 = {biasA0,biasA0,biasA0,biasA0};
        f4v A1 = {biasA1,biasA1,biasA1,biasA1};
        // --- emb phase (static TOK, plain cached loads) BEFORE the poll ---
        #pragma unroll
        for(int kc=0;kc<8;++kc){
          s8v a = ld16(er + kc*32 + q*8);
          A0 = MFMA(a, wxa[kc], A0); A1 = MFMA(a, wxb[kc], A1);
        }
        poll_n64(g_slot0 + dir*64, i0);        // same-dir wave0 peers completed step i0-1
        // --- counted bypass H stream: 32 loads (f: plane=f&1, kc=f>>1), depth 16 ---
        s8v hst[16];
#define H0ISS(f) ldc(hst[(f)], Hr + (((f)&1)?8192u:0u) + (size_t)m*H_ + (((f)>>1)*32) + q*8);
#define H0STEP(f) { \
        waitv<(((f)<16)?15:(31-(f)))>(hst[(f)&15]); \
        A0 = MFMA(hst[(f)&15], w0a[(f)>>1], A0); \
        A1 = MFMA(hst[(f)&15], w0b[(f)>>1], A1); \
        if((f)+16<32) ldc(hst[(f)&15], Hr + (((f)&1)?8192u:0u) + (size_t)m*H_ + (((((f)+16))>>1)*32) + q*8); }
        RPT16(H0ISS,0)
        RPT16(H0STEP,0) RPT16(H0STEP,16)
        float hn0 = gate_combine(A0, cA0, l);
        float hn1 = gate_combine(A1, cA1, l);
        u16 h0h=f2bf(hn0), h0l=f2bf(hn0 - bf2f(h0h));
        u16 h1h=f2bf(hn1), h1l=f2bf(hn1 - bf2f(h1h));
        u16* Hw = g_H0 + (size_t)(dir*2 + (p0^1))*16384;
        st2c(Hw + (size_t)bo*H_ + hc0, h0h); st2c(Hw + 8192 + (size_t)bo*H_ + hc0, h0l);
        st2c(Hw + (size_t)bo*H_ + hc1, h1h); st2c(Hw + 8192 + (size_t)bo*H_ + hc1, h1l);
        u16* Xw = g_X1 + (size_t)(k&3)*327680;          // 4-deep call buffer
        size_t xr = ((size_t)row*16 + bo)*H2 + dir*H_;
        if(s==Lk-1){
          // final step of call: X1 must be mall-visible under the call-granular flag
          st2c(Xw + xr + hc0, h0h); st2c(Xw + 163840 + xr + hc0, h0l);
          st2c(Xw + xr + hc1, h1h); st2c(Xw + 163840 + xr + hc1, h1l);
          publish_slot(&g_slot0[blk], i0+1);
        } else {
          publish_slot(&g_slot0[blk], i0+1);            // drains the 4 H stores only
          st2c(Xw + xr + hc0, h0h); st2c(Xw + 163840 + xr + hc0, h0l);
          st2c(Xw + xr + hc1, h1h); st2c(Xw + 163840 + xr + hc1, h1l);
        }
        ++i0; p0 ^= 1;
      }
    }
  } else {
    // =================== layer-1 engine: 275 steps, trails wave0 ===================
    u32 i1 = 0, Sc = 0; int p1 = 0;
    f4v A0, A1;
    s8v sh[12], sl[12];
#define XISS8(kc) { ldc(sh[(kc)], Xr + (size_t)m*H2 + ((kc)*32) + q*8); \
                    ldc(sl[(kc)], Xr2 + (size_t)m*H2 + ((kc)*32) + q*8); }
#define XSTEP8(kc) { \
        waitv2<(((kc)<24)?14:(2*(31-(kc))))>(sh[(kc)&7], sl[(kc)&7]); \
        s8v bf0 = ld16(sw + (kc)*512 + l8); \
        s8v bf1 = ld16(sw + 24576 + (kc)*512 + l8); \
        A0 = MFMA(sh[(kc)&7], bf0, A0); A0 = MFMA(sl[(kc)&7], bf0, A0); \
        A1 = MFMA(sh[(kc)&7], bf1, A1); A1 = MFMA(sl[(kc)&7], bf1, A1); \
        if((kc)+8<32){ ldc(sh[(kc)&7], Xr + (size_t)m*H2 + (((kc)+8)*32) + q*8); \
                       ldc(sl[(kc)&7], Xr2 + (size_t)m*H2 + (((kc)+8)*32) + q*8); } }
#define XPHASE(rowv) { \
        const u16* Xr  = Xbase + ((size_t)(rowv)*16)*H2; \
        const u16* Xr2 = Xr + 163840; \
        A0 = (f4v){biasB0,biasB0,biasB0,biasB0}; \
        A1 = (f4v){biasB1,biasB1,biasB1,biasB1}; \
        RPT8(XISS8,0) \
        RPT16(XSTEP8,0) RPT16(XSTEP8,16) }
#define H1ISS(h) { ldc(sh[(h)], Hr1 + (size_t)m*H_ + ((h)*32) + q*8); \
                   ldc(sl[(h)], Hr1 + 8192 + (size_t)m*H_ + ((h)*32) + q*8); }
#define H1STEP(h) { \
        waitv2<(((h)<4)?22:(30-2*(h)))>(sh[(h)%12], sl[(h)%12]); \
        s8v bf0 = ld16(sw + (32+(h))*512 + l8); \
        s8v bf1 = ld16(sw + 24576 + (32+(h))*512 + l8); \
        A0 = MFMA(sh[(h)%12], bf0, A0); A0 = MFMA(sl[(h)%12], bf0, A0); \
        A1 = MFMA(sh[(h)%12], bf1, A1); A1 = MFMA(sl[(h)%12], bf1, A1); \
        if((h)+12<16){ ldc(sh[(h)%12], Hr1 + (size_t)m*H_ + (((h)+12)*32) + q*8); \
                       ldc(sl[(h)%12], Hr1 + 8192 + (size_t)m*H_ + (((h)+12)*32) + q*8); } }
    for(int cl=0; cl<50; ++cl){
      int Lc = cl/5 + 1; int n1 = cl - (cl/5)*5;
      // X1[cl] frozen once wave0 (both dirs) finished call cl
      poll_n128(g_slot0, Sc + (u32)Lc);
      const u16* Xbase = g_X1 + (size_t)(cl&3)*327680;
      XPHASE(dir ? (Lc-1) : 0)                       // X-phase for s=0
      for(int s=0; s<Lc; ++s){
        int row = dir ? (Lc-1-s) : s;
        const u16* Hr1 = g_H1 + (size_t)(dir*2 + p1)*16384;
        // --- recurrence poll: same-dir wave1 peers completed step i1-1 ---
        poll_n64(g_slot1 + dir*64, i1);
        // --- counted bypass H1 stream: pairs h=0..15 (hi,lo), depth 12 pairs ---
        RPT8(H1ISS,0) RPT4(H1ISS,8)
        RPT16(H1STEP,0)
        float hn0 = gate_combine(A0, cB0, l);
        float hn1 = gate_combine(A1, cB1, l);
        u16 h0h=f2bf(hn0), h0l=f2bf(hn0 - bf2f(h0h));
        u16 h1h=f2bf(hn1), h1l=f2bf(hn1 - bf2f(h1h));
        u16* Hw = g_H1 + (size_t)(dir*2 + (p1^1))*16384;
        st2c(Hw + (size_t)bo*H_ + hc0, h0h); st2c(Hw + 8192 + (size_t)bo*H_ + hc0, h0l);
        st2c(Hw + (size_t)bo*H_ + hc1, h1h); st2c(Hw + 8192 + (size_t)bo*H_ + hc1, h1l);
        publish_slot(&g_slot1[blk], i1+1);           // drains the 4 H1 stores
        // --- bubble fill: X-phase of step s+1 (frozen data, no poll needed) ---
        if(s+1<Lc){ XPHASE(dir ? (Lc-2-s) : (s+1)) }
        // --- OUT1 stores (consumed only by k3 after kernel end) ---
        size_t orow = (size_t)(n1*10 + row)*16 + bo;
        st2c(g_OUT1 + orow*H2 + dir*H_ + hc0, h0h);
        st2c(g_OUT1 + (size_t)800*H2 + orow*H2 + dir*H_ + hc0, h0l);
        st2c(g_OUT1 + orow*H2 + dir*H_ + hc1, h1h);
        st2c(g_OUT1 + (size_t)800*H2 + orow*H2 + dir*H_ + hc1, h1l);
        ++i1; p1 ^= 1;
      }
      Sc += (u32)Lc;
    }
  }
}

// =====================  K3: out = OUT1(800x1024 hi/lo) @ Wfc(1024x30000) + bfc =====================
__global__ __launch_bounds__(256,1) void k3(const void* Wfc, const void* bfc, void* out){
  int f32 = (int)g_flag;
  int w = threadIdx.x>>6, l = threadIdx.x&63, q = l>>4, c = l&15, m = l&15;
  int ct = blockIdx.x*4 + w;
  if(ct >= 1875) return;
  int col = ct*16 + c;
  s8v bfr[32];
  #pragma unroll
  for(int kc=0; kc<32; ++kc){
    #pragma unroll
    for(int j=0;j<8;++j) bfr[kc][j] = (short)ldw(Wfc, (size_t)(kc*32+q*8+j)*V_ + col, f32);
  }
  float bi = ldwf(bfc, col, f32);
  for(int rt=0; rt<50; ++rt){
    f4v acc = {0.f,0.f,0.f,0.f};
    const u16* Ah = g_OUT1 + (size_t)(rt*16 + m)*H2;
    const u16* Al = Ah + (size_t)800*H2;
    #pragma unroll
    for(int kc=0; kc<32; ++kc){
      acc = MFMA(ld16(Ah + kc*32 + q*8), bfr[kc], acc);
      acc = MFMA(ld16(Al + kc*32 + q*8), bfr[kc], acc);
    }
    if(f32){
      float* o = (float*)out;
      #pragma unroll
      for(int r=0;r<4;++r) o[(size_t)(rt*16 + q*4 + r)*V_ + col] = acc[r] + bi;
    } else {
      u16* o = (u16*)out;
      #pragma unroll
      for(int r=0;r<4;++r) o[(size_t)(rt*16 + q*4 + r)*V_ + col] = f2bf(acc[r] + bi);
    }
  }
}

// =====================  launcher  =====================
extern "C" void kernel_launch(void* const* d_in, const int* in_sizes, int n_in,
                              void* d_out, int out_size, void* d_ws, size_t ws_size,
                              hipStream_t stream){
  (void)in_sizes; (void)n_in; (void)out_size; (void)d_ws; (void)ws_size;
  const void* img  = d_in[0];
  const int*  caps = (const int*)d_in[1];
  const void* Wh1=d_in[2],  *bh1=d_in[3];
  const void* Wh2=d_in[4],  *bh2=d_in[5];
  const void* Wc1=d_in[6],  *bc1=d_in[7];
  const void* Wc2=d_in[8],  *bc2=d_in[9];
  const void* emb=d_in[10];
  const void* Wih0f=d_in[11], *Whh0f=d_in[12], *b0f=d_in[13];
  const void* Wih0b=d_in[14], *Whh0b=d_in[15], *b0b=d_in[16];
  const void* Wih1f=d_in[17], *Whh1f=d_in[18], *b1f=d_in[19];
  const void* Wih1b=d_in[20], *Whh1b=d_in[21], *b1b=d_in[22];
  const void* Wfc=d_in[23],  *bfc=d_in[24];

  hipLaunchKernelGGL(k0,    dim3(1),     dim3(64),  0, stream, img);
  hipLaunchKernelGGL(k_tok, dim3(800),   dim3(256), 0, stream, caps, emb);
  hipLaunchKernelGGL(k1a,   dim3(32),    dim3(256), 0, stream, img, Wh1, bh1, Wc1, bc1);
  hipLaunchKernelGGL(k1b,   dim3(16),    dim3(256), 0, stream, Wh2, bh2, Wc2, bc2);
  hipLaunchKernelGGL(k2,    dim3(NCOMP), dim3(128), 0, stream,
                     Wih0f, Whh0f, b0f, Wih0b, Whh0b, b0b,
                     Wih1f, Whh1f, b1f, Wih1b, Whh1b, b1b);
  hipLaunchKernelGGL(k3,    dim3(469),   dim3(256), 0, stream, Wfc, bfc, d_out);
}

// Round 6
// 3620.834 us; speedup vs baseline: 1.0650x; 1.0650x over previous
//
#include <hip/hip_runtime.h>

typedef unsigned short u16;
typedef unsigned int   u32;
typedef unsigned long long u64;
typedef __attribute__((ext_vector_type(8))) short s8v;   // 8 x bf16 (4 VGPRs)
typedef __attribute__((ext_vector_type(4))) float f4v;   // MFMA accumulator

#define DEVI __device__ __forceinline__

// ---- problem constants ----
#define B_  16
#define N_  5
#define T_  10
#define H_  512
#define E_  250
#define V_  30000
#define F_  2048
#define FH  2048   // 4H
#define H2  1024   // 2H
#define NCOMP 128  // compute blocks: dir(2) x 64 col-groups, 2 waves each

// ---- static device scratch (no d_ws dependence) ----
__device__ u32   g_flag;                  // 1 = inputs are float32, 0 = bf16
__device__ u32   g_slot[NCOMP];           // barrier arrival epochs (per block)
__device__ __attribute__((aligned(64))) u16   g_H0[4*2*16*512];   // [(dir*2+par)][plane][16][512]
__device__ __attribute__((aligned(64))) u16   g_H1[4*2*16*512];
__device__ __attribute__((aligned(64))) float g_cinit[16*512];
__device__ __attribute__((aligned(64))) u16   g_A1[2*2*16*1024];  // [which][plane][16][1024]
__device__ __attribute__((aligned(64))) u16   g_X1[2*2*10*16*1024]; // [callpar][plane][row*16+b][1024]
__device__ __attribute__((aligned(64))) u16   g_OUT1[2*800*1024]; // [plane][orow][1024]
__device__ __attribute__((aligned(64))) u16   g_TOK[800*256];     // [(b*5+n)*10+r][256] bf16

DEVI f4v MFMA(s8v a, s8v b, f4v c){ return __builtin_amdgcn_mfma_f32_16x16x32_bf16(a,b,c,0,0,0); }
DEVI float bf2f(u16 u){ union{u32 i; float f;} v; v.i = ((u32)u)<<16; return v.f; }
DEVI u16 f2bf(float f){ union{float f; u32 i;} v; v.f = f; u32 i = v.i + 0x7fffu + ((v.i>>16)&1u); return (u16)(i>>16); }
DEVI float sigm(float x){ return 1.0f/(1.0f+__expf(-x)); }
DEVI float tanhfast(float x){ float e = __expf(2.0f*x); return 1.0f - 2.0f/(e+1.0f); }

DEVI s8v ld16(const u16* p){ return *(const s8v*)p; }                 // 16B-aligned, cached
DEVI s8v ld16u(const u16* p){ s8v a; __builtin_memcpy(&a, p, 16); return a; }

// bypassing 16B load issue (sc0 sc1 -> served at mall, no stale L1/L2). Completion is
// tracked manually via counted vmcnt waits tied to the dest regs ("+v") so consuming
// MFMAs cannot be scheduled above the wait.
DEVI void ldc(s8v& d, const u16* p){
  asm volatile("global_load_dwordx4 %0, %1, off sc0 sc1" : "=v"(d) : "v"(p));
}
template<int N> DEVI void waitv(s8v& a){
  asm volatile("s_waitcnt vmcnt(%1)" : "+v"(a) : "n"(N));
}
template<int N> DEVI void waitv2(s8v& a, s8v& b){
  asm volatile("s_waitcnt vmcnt(%2)" : "+v"(a), "+v"(b) : "n"(N));
}

// coherent write-through stores (sc0 sc1): visible at mall, never dirty in L2
DEVI void st2c(u16* p, u16 v){
  asm volatile("global_store_short %0, %1, off sc0 sc1" :: "v"(p), "v"((u32)v) : "memory");
}
DEVI void st16c(u16* p, s8v v){
  asm volatile("global_store_dwordx4 %0, %1, off sc0 sc1" :: "v"(p), "v"(v) : "memory");
}

// dtype-flexible element accessors (flag is wave-uniform)
DEVI u16 ldw(const void* W, size_t idx, int f32){
  return f32 ? f2bf(((const float*)W)[idx]) : ((const u16*)W)[idx];
}
DEVI float ldwf(const void* W, size_t idx, int f32){
  return f32 ? ((const float*)W)[idx] : bf2f(((const u16*)W)[idx]);
}
DEVI s8v ldA8(const void* A, size_t idx, int f32){
  if(f32){
    const float* p = (const float*)A + idx;
    s8v a;
    #pragma unroll
    for(int j=0;j<8;++j) a[j] = (short)f2bf(p[j]);
    return a;
  }
  return ld16u((const u16*)A + idx);
}
DEVI s8v gatherBf(const void* W, int ld, int row0, int col, int f32){
  s8v r;
  #pragma unroll
  for(int j=0;j<8;++j) r[j] = (short)ldw(W, (size_t)(row0+j)*ld + col, f32);
  return r;
}

// repeat macros (manual unroll keeps every index/template-arg a literal constant)
#define RPT4(M,b)  M(b) M((b)+1) M((b)+2) M((b)+3)
#define RPT8(M,b)  RPT4(M,b) RPT4(M,(b)+4)
#define RPT16(M,b) RPT8(M,b) RPT8(M,(b)+8)

// =====================  K0: dtype sniff + barrier state reset  =====================
__global__ __launch_bounds__(64) void k0(const void* img){
  int l = threadIdx.x;
  const u16* p = (const u16*)img;
  int bad = 0;
  #pragma unroll
  for(int i=0;i<4;++i){
    float v = bf2f(p[l + 64*i]);      // f32 data => half these are mantissa garbage
    if(!(fabsf(v) <= 1e4f)) bad = 1;  // catches huge exponents AND NaN
  }
  unsigned long long mb = __ballot(bad);
  g_slot[l] = 0u; g_slot[l+64] = 0u;
  if(l==0){ g_flag = (mb != 0ull) ? 1u : 0u; }
}

// =====================  K_tok: compact bf16 token-embedding table  =====================
__global__ __launch_bounds__(256) void k_tok(const int* caps, const void* emb){
  int f32 = (int)g_flag;
  int idx = blockIdx.x*256 + threadIdx.x;     // 0 .. 800*256-1
  int bnr = idx>>8, e = idx&255;
  int tok = caps[bnr];
  u16 v = (e < E_) ? ldw(emb, (size_t)tok*E_ + e, f32) : (u16)0;
  g_TOK[idx] = v;
}

// =====================  K1a: A1 = relu(img@Wh1+bh1), C1 = relu(img@Wc1+bc1) =====================
__global__ __launch_bounds__(256) void k1a(const void* img, const void* Wh1, const void* bh1,
                                           const void* Wc1, const void* bc1){
  int f32 = (int)g_flag;
  int w = threadIdx.x>>6, l = threadIdx.x&63, q = l>>4, c = l&15, m = l&15;
  int widx = blockIdx.x*4 + w;         // 0..127
  int which = widx>>6;                 // 0=h path, 1=c path
  int ct    = widx&63;                 // 64 col tiles
  const void* W    = which? Wc1 : Wh1;
  const void* bias = which? bc1 : bh1;
  int col = ct*16 + c;
  f4v acc = {0.f,0.f,0.f,0.f};
  #pragma unroll 4
  for(int kc=0; kc<64; ++kc){
    s8v a = ldA8(img, (size_t)m*F_ + kc*32 + q*8, f32);
    s8v b = gatherBf(W, H2, kc*32+q*8, col, f32);
    acc = MFMA(a,b,acc);
  }
  float bi = ldwf(bias, col, f32);
  #pragma unroll
  for(int r=0;r<4;++r){
    float v = fmaxf(acc[r]+bi, 0.f);
    u16 hi = f2bf(v); u16 lo = f2bf(v - bf2f(hi));
    int rowb = q*4+r;
    g_A1[(size_t)(which*2+0)*B_*H2 + (size_t)rowb*H2 + col] = hi;
    g_A1[(size_t)(which*2+1)*B_*H2 + (size_t)rowb*H2 + col] = lo;
  }
}

// =====================  K1b: h,c = relu(A1@Wh2+bh2) etc; init H bufs (parity 0), cinit =====================
__global__ __launch_bounds__(256) void k1b(const void* Wh2, const void* bh2,
                                           const void* Wc2, const void* bc2){
  int f32 = (int)g_flag;
  int w = threadIdx.x>>6, l = threadIdx.x&63, q = l>>4, c = l&15, m = l&15;
  int widx = blockIdx.x*4 + w;         // 0..63
  int which = widx>>5;                 // 0=h, 1=c
  int ct    = widx&31;                 // 32 col tiles (H=512)
  const void* W    = which? Wc2 : Wh2;
  const void* bias = which? bc2 : bh2;
  const u16* Ab    = g_A1 + (size_t)which*2*B_*H2;
  int col = ct*16 + c;
  f4v acc = {0.f,0.f,0.f,0.f};
  #pragma unroll 4
  for(int kc=0; kc<32; ++kc){
    s8v ah = ld16(Ab + (size_t)m*H2 + kc*32 + q*8);
    s8v al = ld16(Ab + (size_t)B_*H2 + (size_t)m*H2 + kc*32 + q*8);
    s8v b  = gatherBf(W, H_, kc*32+q*8, col, f32);
    acc = MFMA(ah,b,acc);
    acc = MFMA(al,b,acc);
  }
  float bi = ldwf(bias, col, f32);
  #pragma unroll
  for(int r=0;r<4;++r){
    float v = fmaxf(acc[r]+bi, 0.f);
    int rowb = q*4+r;
    if(which==0){
      u16 hi = f2bf(v); u16 lo = f2bf(v - bf2f(hi));
      #pragma unroll
      for(int dir=0; dir<2; ++dir){
        size_t base = (size_t)(dir*2+0)*16384;      // parity 0
        g_H0[base + 0*8192 + rowb*512 + col] = hi;  g_H0[base + 1*8192 + rowb*512 + col] = lo;
        g_H1[base + 0*8192 + rowb*512 + col] = hi;  g_H1[base + 1*8192 + rowb*512 + col] = lo;
      }
    } else {
      g_cinit[(size_t)rowb*H_ + col] = v;
    }
  }
}

// ========== dataflow flags (BSP, no coordinator, no cache invalidation) =========
DEVI void flag_publish(u32 ep){
  asm volatile("s_waitcnt vmcnt(0)" ::: "memory");   // data stores acked at mall
  __syncthreads();                                    // both waves of the block done
  if(threadIdx.x==0)
    __hip_atomic_store(&g_slot[blockIdx.x], ep, __ATOMIC_RELAXED, __HIP_MEMORY_SCOPE_SYSTEM);
}
DEVI void flag_poll(u32 ep){
  int l = threadIdx.x & 63;
  for(;;){
    u32 a = __hip_atomic_load(&g_slot[l],    __ATOMIC_RELAXED, __HIP_MEMORY_SCOPE_SYSTEM);
    u32 b = __hip_atomic_load(&g_slot[l+64], __ATOMIC_RELAXED, __HIP_MEMORY_SCOPE_SYSTEM);
    if(__all((int)(a>=ep && b>=ep))) break;
    __builtin_amdgcn_s_sleep(1);
  }
  asm volatile("s_waitcnt vmcnt(0)" ::: "memory");   // clean vmcnt before counted phases
}

// gate combine: acc holds G[batch=4q+r][col c], cols = gate(c>>2) x hcol(c&3).
DEVI float gate_combine(f4v acc, float& cs, int l){
  int base = (l & 48) | (l & 3);
  int sel  = (l >> 2) & 3;
  float G[4];
  #pragma unroll
  for(int gg=0; gg<4; ++gg){
    int src = base | (gg<<2);
    float a0 = __shfl(acc[0], src, 64);
    float a1 = __shfl(acc[1], src, 64);
    float a2 = __shfl(acc[2], src, 64);
    float a3 = __shfl(acc[3], src, 64);
    float x = (sel&1)? a1 : a0;
    float y = (sel&1)? a3 : a2;
    G[gg] = (sel&2)? y : x;
  }
  float iG = sigm(G[0]);
  float fG = sigm(G[1]);
  float gG = tanhfast(G[2]);
  float oG = sigm(G[3]);
  cs = fG*cs + iG*gG;
  return oG * tanhfast(cs);
}

// =====================  K2: persistent pipelined bilstm2 x 50 (BSP, coalesced stores) ==========
// 128 blocks x 128 threads (2 waves). Block: dir = blk>=64, 8 h-cols. wave0 = layer-0 engine
// (weights in VGPRs), wave1 = layer-1 engine lagged one call ([Wih1;Whh1] in 96KB LDS,
// lane-major = conflict-free). 285 supersteps. Column map: lane owns ADJACENT cols
// (hc0=hb+2*(c&3), hc1=hc0+1) so h-state is written via wave-local LDS transpose +
// 16B coalesced sc0sc1 stores (64 x 16B per wave-step instead of 512 x 2B scattered).
__global__ __launch_bounds__(128) void k2(const void* Wih0f, const void* Whh0f, const void* b0f,
                                          const void* Wih0b, const void* Whh0b, const void* b0b,
                                          const void* Wih1f, const void* Whh1f, const void* b1f,
                                          const void* Wih1b, const void* Whh1b, const void* b1b){
  __shared__ u16 sw[2*24576];                  // 96 KB: [tile][kc48][lane64][j8]
  __shared__ __attribute__((aligned(16))) u32 tr0[128];  // wave0 transpose scratch [plane][row][pair]
  __shared__ __attribute__((aligned(16))) u32 tr1[128];  // wave1 transpose scratch
  int tid = threadIdx.x;
  int blk = blockIdx.x;
  int f32 = (int)g_flag;
  int wv  = tid>>6;                            // 0 = layer-0 wave, 1 = layer-1 wave
  int l   = tid&63;
  int q = l>>4, c = l&15, m = l&15;
  int l8 = l*8;                                // lane-major LDS read offset (u16 units)
  int dir = blk>>6; int blkd = blk&63;
  int hb  = blkd*8;                            // 8 owned h-cols
  int gc0 = (c>>2)*512 + hb + 2*(c&3);         // lane's G-column, tile 0 (even local col)
  int gc1 = gc0 + 1;                           // tile 1 (odd local col)
  int bo  = q*4 + (c>>2);                      // owned batch row
  int hc0 = hb + 2*(c&3), hc1 = hc0 + 1;       // owned h-cols (adjacent pair)

  const void* Wih0 = dir? Wih0b : Wih0f;
  const void* Whh0 = dir? Whh0b : Whh0f;
  const void* b0   = dir? b0b   : b0f;
  const void* Wih1 = dir? Wih1b : Wih1f;
  const void* Whh1 = dir? Whh1b : Whh1f;
  const void* b1   = dir? b1b   : b1f;

  // ---- layer-1 B-fragments for both tiles in LDS (lane-major layout) ----
  for(int tt=0; tt<2; ++tt){
    for(int ii=tid; ii<24576; ii+=128){
      int kc = ii>>9;
      int lane = (ii>>3)&63;
      int j  = ii&7;
      int cc = lane&15, qq = lane>>4;
      int gc = (cc>>2)*512 + hb + 2*(cc&3) + tt;
      int rowk = kc*32+qq*8+j;
      sw[tt*24576+ii] = (rowk < H2) ? ldw(Wih1, (size_t)rowk*FH + gc, f32)
                                    : ldw(Whh1, (size_t)(rowk-H2)*FH + gc, f32);
    }
  }

  // ---- per-wave persistent state ----
  s8v w0a[16], w0b[16], wxa[8], wxb[8];        // wave0 only: layer-0 B-frags in regs
  float cA0=0.f, cA1=0.f, biasA0=0.f, biasA1=0.f;   // wave0 (layer-0 cell state)
  float cB0=0.f, cB1=0.f, biasB0=0.f, biasB1=0.f;   // wave1 (layer-1 cell state)
  if(wv==0){
    #pragma unroll
    for(int kc=0;kc<16;++kc){
      #pragma unroll
      for(int j=0;j<8;++j){
        int rowk = kc*32+q*8+j;
        w0a[kc][j] = (short)ldw(Whh0, (size_t)rowk*FH + gc0, f32);
        w0b[kc][j] = (short)ldw(Whh0, (size_t)rowk*FH + gc1, f32);
      }
    }
    #pragma unroll
    for(int kc=0;kc<8;++kc){
      #pragma unroll
      for(int j=0;j<8;++j){
        int rowk = kc*32+q*8+j;
        wxa[kc][j] = (rowk<E_)? (short)ldw(Wih0, (size_t)rowk*FH + gc0, f32) : (short)0;
        wxb[kc][j] = (rowk<E_)? (short)ldw(Wih0, (size_t)rowk*FH + gc1, f32) : (short)0;
      }
    }
    biasA0 = ldwf(b0, gc0, f32); biasA1 = ldwf(b0, gc1, f32);
    cA0 = g_cinit[(size_t)bo*H_ + hc0]; cA1 = g_cinit[(size_t)bo*H_ + hc1];
  } else {
    biasB0 = ldwf(b1, gc0, f32); biasB1 = ldwf(b1, gc1, f32);
    cB0 = g_cinit[(size_t)bo*H_ + hc0]; cB1 = g_cinit[(size_t)bo*H_ + hc1];
  }
  __syncthreads();

  u32 ep = 0;
  int p0 = 0, p1 = 0;
  // superstep schedule: layer-0 runs call k, layer-1 runs call k-1 (lengths are
  // non-decreasing so layer-1 never starves). k==50 is the pure layer-1 tail.
  for(int k=0; k<=50; ++k){
    int Lk = (k<50) ? (k/5 + 1) : 10;
    int Lp = (k==0) ? 0 : ((k-1)/5 + 1);
    int n0 = k - (k/5)*5;
    int km = k-1;
    int n1 = (k>0) ? (km - (km/5)*5) : 0;
    for(int s=0; s<Lk; ++s){
      if(wv==0){
        if(k<50){
          int row = dir ? (Lk-1-s) : s;
          const u16* er = g_TOK + ((size_t)(m*N_ + n0)*T_ + row)*256;
          const u16* Hr = g_H0 + (size_t)(dir*2 + p0)*16384;
          f4v A0 = {biasA0,biasA0,biasA0,biasA0};
          f4v A1 = {biasA1,biasA1,biasA1,biasA1};
          // --- emb phase (static TOK, plain cached loads) BEFORE the poll ---
          #pragma unroll
          for(int kc=0;kc<8;++kc){
            s8v a = ld16(er + kc*32 + q*8);
            A0 = MFMA(a, wxa[kc], A0); A1 = MFMA(a, wxb[kc], A1);
          }
          flag_poll(ep);
          // --- counted bypass H stream: 32 loads (f: plane=f&1, kc=f>>1), depth 16 ---
          s8v hst[16];
#define H0ISS(f) ldc(hst[(f)], Hr + (((f)&1)?8192u:0u) + (size_t)m*H_ + (((f)>>1)*32) + q*8);
#define H0STEP(f) { \
          waitv<(((f)<16)?15:(31-(f)))>(hst[(f)&15]); \
          A0 = MFMA(hst[(f)&15], w0a[(f)>>1], A0); \
          A1 = MFMA(hst[(f)&15], w0b[(f)>>1], A1); \
          if((f)+16<32) ldc(hst[(f)&15], Hr + (((f)&1)?8192u:0u) + (size_t)m*H_ + (((((f)+16))>>1)*32) + q*8); }
          RPT16(H0ISS,0)
          RPT16(H0STEP,0) RPT16(H0STEP,16)
          float hn0 = gate_combine(A0, cA0, l);
          float hn1 = gate_combine(A1, cA1, l);
          u16 h0h=f2bf(hn0), h0l=f2bf(hn0 - bf2f(h0h));
          u16 h1h=f2bf(hn1), h1l=f2bf(hn1 - bf2f(h1h));
          // --- wave-local LDS transpose -> coalesced 16B write-through stores ---
          tr0[(c&3) + bo*4]      = (u32)h0h | ((u32)h1h<<16);
          tr0[64 + (c&3) + bo*4] = (u32)h0l | ((u32)h1l<<16);
          asm volatile("s_waitcnt lgkmcnt(0)" ::: "memory");
          if(l<32){
            s8v v = *(const s8v*)&tr0[l*4];
            int pl2 = l>>4, rw = l&15;
            u16* Hw = g_H0 + (size_t)(dir*2 + (p0^1))*16384;
            st16c(Hw + pl2*8192 + rw*512 + hb, v);
            u16* Xw = g_X1 + (size_t)(k&1)*327680;          // call-parity double buffer
            st16c(Xw + (size_t)pl2*163840 + ((size_t)row*16 + rw)*H2 + dir*H_ + hb, v);
          }
          p0 ^= 1;
        }
      } else {
        if(k>0 && s<Lp){
          int row = dir ? (Lp-1-s) : s;
          const u16* Xr  = g_X1 + (size_t)(km&1)*327680 + ((size_t)row*16)*H2;
          const u16* Xr2 = Xr + 163840;
          const u16* Hr1 = g_H1 + (size_t)(dir*2 + p1)*16384;
          f4v A0 = {biasB0,biasB0,biasB0,biasB0};
          f4v A1 = {biasB1,biasB1,biasB1,biasB1};
          s8v sh[12], sl[12];
          // X1 of call k-1 is stable during call k's steps for s>0 (same-parity writers
          // only exist at call k+1, which the barrier forbids). At s==0 the last X1 rows
          // were written in superstep ep-1 -> must poll first.
          if(s==0) flag_poll(ep);
          // --- counted bypass X stream: pairs kc=0..31 (hi,lo), depth 12 pairs ---
#define XISS(kc) { ldc(sh[(kc)], Xr + (size_t)m*H2 + ((kc)*32) + q*8); \
                   ldc(sl[(kc)], Xr2 + (size_t)m*H2 + ((kc)*32) + q*8); }
#define XSTEP(kc) { \
          waitv2<(((kc)<20)?22:(62-2*(kc)))>(sh[(kc)%12], sl[(kc)%12]); \
          s8v bf0 = ld16(sw + (kc)*512 + l8); \
          s8v bf1 = ld16(sw + 24576 + (kc)*512 + l8); \
          A0 = MFMA(sh[(kc)%12], bf0, A0); A0 = MFMA(sl[(kc)%12], bf0, A0); \
          A1 = MFMA(sh[(kc)%12], bf1, A1); A1 = MFMA(sl[(kc)%12], bf1, A1); \
          if((kc)+12<32){ ldc(sh[(kc)%12], Xr + (size_t)m*H2 + (((kc)+12)*32) + q*8); \
                          ldc(sl[(kc)%12], Xr2 + (size_t)m*H2 + (((kc)+12)*32) + q*8); } }
          RPT8(XISS,0) RPT4(XISS,8)
          RPT16(XSTEP,0) RPT16(XSTEP,16)
          if(s>0) flag_poll(ep);
          // --- counted bypass H1 stream: pairs h=0..15 (hi,lo), depth 12 pairs ---
#define H1ISS(h) { ldc(sh[(h)], Hr1 + (size_t)m*H_ + ((h)*32) + q*8); \
                   ldc(sl[(h)], Hr1 + 8192 + (size_t)m*H_ + ((h)*32) + q*8); }
#define H1STEP(h) { \
          waitv2<(((h)<4)?22:(30-2*(h)))>(sh[(h)%12], sl[(h)%12]); \
          s8v bf0 = ld16(sw + (32+(h))*512 + l8); \
          s8v bf1 = ld16(sw + 24576 + (32+(h))*512 + l8); \
          A0 = MFMA(sh[(h)%12], bf0, A0); A0 = MFMA(sl[(h)%12], bf0, A0); \
          A1 = MFMA(sh[(h)%12], bf1, A1); A1 = MFMA(sl[(h)%12], bf1, A1); \
          if((h)+12<16){ ldc(sh[(h)%12], Hr1 + (size_t)m*H_ + (((h)+12)*32) + q*8); \
                         ldc(sl[(h)%12], Hr1 + 8192 + (size_t)m*H_ + (((h)+12)*32) + q*8); } }
          RPT8(H1ISS,0) RPT4(H1ISS,8)
          RPT16(H1STEP,0)
          float hn0 = gate_combine(A0, cB0, l);
          float hn1 = gate_combine(A1, cB1, l);
          u16 h0h=f2bf(hn0), h0l=f2bf(hn0 - bf2f(h0h));
          u16 h1h=f2bf(hn1), h1l=f2bf(hn1 - bf2f(h1h));
          // --- wave-local LDS transpose -> coalesced 16B write-through stores ---
          tr1[(c&3) + bo*4]      = (u32)h0h | ((u32)h1h<<16);
          tr1[64 + (c&3) + bo*4] = (u32)h0l | ((u32)h1l<<16);
          asm volatile("s_waitcnt lgkmcnt(0)" ::: "memory");
          if(l<32){
            s8v v = *(const s8v*)&tr1[l*4];
            int pl2 = l>>4, rw = l&15;
            u16* Hw = g_H1 + (size_t)(dir*2 + (p1^1))*16384;
            st16c(Hw + pl2*8192 + rw*512 + hb, v);
            size_t orow = (size_t)(n1*10 + row)*16 + rw;
            st16c(g_OUT1 + (size_t)pl2*819200 + orow*H2 + dir*H_ + hb, v);
          }
          p1 ^= 1;
        }
      }
      flag_publish(ep+1);
      ++ep;
    }
  }
}

// =====================  K3: out = OUT1(800x1024 hi/lo) @ Wfc(1024x30000) + bfc =====================
__global__ __launch_bounds__(256,1) void k3(const void* Wfc, const void* bfc, void* out){
  int f32 = (int)g_flag;
  int w = threadIdx.x>>6, l = threadIdx.x&63, q = l>>4, c = l&15, m = l&15;
  int ct = blockIdx.x*4 + w;
  if(ct >= 1875) return;
  int col = ct*16 + c;
  s8v bfr[32];
  #pragma unroll
  for(int kc=0; kc<32; ++kc){
    #pragma unroll
    for(int j=0;j<8;++j) bfr[kc][j] = (short)ldw(Wfc, (size_t)(kc*32+q*8+j)*V_ + col, f32);
  }
  float bi = ldwf(bfc, col, f32);
  for(int rt=0; rt<50; ++rt){
    f4v acc = {0.f,0.f,0.f,0.f};
    const u16* Ah = g_OUT1 + (size_t)(rt*16 + m)*H2;
    const u16* Al = Ah + (size_t)800*H2;
    #pragma unroll
    for(int kc=0; kc<32; ++kc){
      acc = MFMA(ld16(Ah + kc*32 + q*8), bfr[kc], acc);
      acc = MFMA(ld16(Al + kc*32 + q*8), bfr[kc], acc);
    }
    if(f32){
      float* o = (float*)out;
      #pragma unroll
      for(int r=0;r<4;++r) o[(size_t)(rt*16 + q*4 + r)*V_ + col] = acc[r] + bi;
    } else {
      u16* o = (u16*)out;
      #pragma unroll
      for(int r=0;r<4;++r) o[(size_t)(rt*16 + q*4 + r)*V_ + col] = f2bf(acc[r] + bi);
    }
  }
}

// =====================  launcher  =====================
extern "C" void kernel_launch(void* const* d_in, const int* in_sizes, int n_in,
                              void* d_out, int out_size, void* d_ws, size_t ws_size,
                              hipStream_t stream){
  (void)in_sizes; (void)n_in; (void)out_size; (void)d_ws; (void)ws_size;
  const void* img  = d_in[0];
  const int*  caps = (const int*)d_in[1];
  const void* Wh1=d_in[2],  *bh1=d_in[3];
  const void* Wh2=d_in[4],  *bh2=d_in[5];
  const void* Wc1=d_in[6],  *bc1=d_in[7];
  const void* Wc2=d_in[8],  *bc2=d_in[9];
  const void* emb=d_in[10];
  const void* Wih0f=d_in[11], *Whh0f=d_in[12], *b0f=d_in[13];
  const void* Wih0b=d_in[14], *Whh0b=d_in[15], *b0b=d_in[16];
  const void* Wih1f=d_in[17], *Whh1f=d_in[18], *b1f=d_in[19];
  const void* Wih1b=d_in[20], *Whh1b=d_in[21], *b1b=d_in[22];
  const void* Wfc=d_in[23],  *bfc=d_in[24];

  hipLaunchKernelGGL(k0,    dim3(1),     dim3(64),  0, stream, img);
  hipLaunchKernelGGL(k_tok, dim3(800),   dim3(256), 0, stream, caps, emb);
  hipLaunchKernelGGL(k1a,   dim3(32),    dim3(256), 0, stream, img, Wh1, bh1, Wc1, bc1);
  hipLaunchKernelGGL(k1b,   dim3(16),    dim3(256), 0, stream, Wh2, bh2, Wc2, bc2);
  hipLaunchKernelGGL(k2,    dim3(NCOMP), dim3(128), 0, stream,
                     Wih0f, Whh0f, b0f, Wih0b, Whh0b, b0b,
                     Wih1f, Whh1f, b1f, Wih1b, Whh1b, b1b);
  hipLaunchKernelGGL(k3,    dim3(469),   dim3(256), 0, stream, Wfc, bfc, d_out);
}